// Round 3
// baseline (3045.546 us; speedup 1.0000x reference)
//
#include <hip/hip_runtime.h>

#define BATCH 512
#define SEQ   128
#define EMBED 300
#define UNITS 512

typedef short  short8   __attribute__((ext_vector_type(8)));
typedef float  floatx16 __attribute__((ext_vector_type(16)));

#define KXF  19    // x K-frags (304 = 19*16)
#define KHF  32    // h K-frags (512 = 32*16)

// LDS: weights only
#define SH_B1  0                     // h rec B cf1: 32 kf * 64 lanes * 16B = 32768
#define SH_B2  32768                 // x B frags: 2 cf * 19 kf * 1024B = 38912
#define SMEM_BYTES (32768 + 38912)   // 71680

// ws layout
#define WS_FLAGS 0                         // 8 groups * 32 WGs * 256B = 64KB (decontended)
#define WS_HBUF  65536                     // 2 buffers * 512 rows * 1024B bf16 row-major
#define WS_NEED  (65536 + 2 * 524288)

__device__ __forceinline__ unsigned short f2bf(float f) {
  union { float f; unsigned u; } v; v.f = f;
  unsigned r = v.u + 0x7fff + ((v.u >> 16) & 1);
  return (unsigned short)(r >> 16);
}
__device__ __forceinline__ float sigm(float x) { return 1.f / (1.f + __expf(-x)); }
__device__ __forceinline__ float tanh_f(float x) {
  float e = __expf(2.f * x);
  return 1.f - 2.f / (e + 1.f);
}

// coherent (LLC-level) exchange primitives
__device__ __forceinline__ void g_store32(unsigned* p, unsigned v) {
  __hip_atomic_store(p, v, __ATOMIC_RELAXED, __HIP_MEMORY_SCOPE_AGENT);
}
__device__ __forceinline__ unsigned long long g_load64(const void* p) {
  return __hip_atomic_load((const unsigned long long*)p, __ATOMIC_RELAXED,
                           __HIP_MEMORY_SCOPE_AGENT);
}
__device__ __forceinline__ short8 ld_frag(const char* p) {
  union { unsigned long long q[2]; short8 s; } u;
  u.q[0] = g_load64(p);
  u.q[1] = g_load64(p + 8);
  return u.s;
}

// wait until all 32 flags of this group reach tgt; lanes 0-31 each own one flag
// (256B stride -> 32 distinct cache lines, 32 loads/WG/round)
__device__ __forceinline__ void poll_ge(const unsigned* gf, int lane, unsigned tgt) {
  const unsigned* p = gf + (lane & 31) * 64;
  for (;;) {
    unsigned v = tgt;
    if (lane < 32)
      v = __hip_atomic_load(p, __ATOMIC_RELAXED, __HIP_MEMORY_SCOPE_AGENT);
    if (__ballot(v >= tgt) == ~0ull) break;
    __builtin_amdgcn_s_sleep(1);
  }
}

#define LDH_GRP(arr, base)                                                  \
  do { _Pragma("unroll")                                                    \
    for (int j = 0; j < 8; ++j) arr[j] = ld_frag(hrow + ((base) + j) * 32); \
  } while (0)

#define MFMA_H_GRP(arr, base)                                                     \
  do { _Pragma("unroll")                                                          \
    for (int j = 0; j < 8; ++j) {                                                 \
      const int kf = (base) + j;                                                  \
      acc0 = __builtin_amdgcn_mfma_f32_32x32x16_bf16(arr[j], b0[kf], acc0, 0,0,0);\
      short8 p1 = *(const short8*)(sh_b1 + (kf * 64 + lane) * 16);                \
      acc1 = __builtin_amdgcn_mfma_f32_32x32x16_bf16(arr[j], p1, acc1, 0,0,0);    \
    }                                                                             \
  } while (0)

extern "C" __global__ void __launch_bounds__(128, 1)
lstm_enc(const int* __restrict__ seq, const float* __restrict__ h0,
         const float* __restrict__ c0, const float* __restrict__ emb,
         const float* __restrict__ kern, const float* __restrict__ rkern,
         const float* __restrict__ bias, float* __restrict__ out,
         char* __restrict__ ws)
{
  extern __shared__ __align__(16) char smem[];
  char* sh_b1 = smem + SH_B1;
  char* sh_b2 = smem + SH_B2;

  const int tid  = threadIdx.x;
  const int lane = tid & 63;
  const int w    = tid >> 6;          // wave: rows w*32..w*32+31 of the 64-row block
  const int rb   = blockIdx.x & 7;    // row-block group
  const int ug   = blockIdx.x >> 3;   // unit block 0..31

  unsigned* gflags = (unsigned*)(ws + WS_FLAGS) + rb * 2048;  // 32 flags * 256B
  unsigned* myflag = gflags + ug * 64;
  char* hb_[2] = { ws + WS_HBUF, ws + WS_HBUF + 524288 };

  const int  n    = lane & 31;
  const int  half = lane >> 5;
  const int  u    = ug * 16 + (n & 15);
  const bool lo   = (n < 16);

  const int gcol0 = (lo ? 0    : 512 ) + (n & 15) + ug * 16;  // [i|f]
  const int gcol1 = (lo ? 1024 : 1536) + (n & 15) + ug * 16;  // [g|o]

  // ---- rec_kernel B-frags: cf0 -> 128 VGPRs, cf1 -> LDS ----
  short8 b0[KHF];
#pragma unroll
  for (int kf = 0; kf < KHF; ++kf) {
    int k0 = kf * 16 + half * 8;
    short8 p0, p1;
#pragma unroll
    for (int j = 0; j < 8; ++j) {
      p0[j] = (short)f2bf(rkern[(k0 + j) * 2048 + gcol0]);
      p1[j] = (short)f2bf(rkern[(k0 + j) * 2048 + gcol1]);
    }
    b0[kf] = p0;
    *(short8*)(sh_b1 + (kf * 64 + lane) * 16) = p1;
  }
  // ---- x-weight B-frags -> LDS ----
#pragma unroll
  for (int kf = 0; kf < KXF; ++kf) {
    int k0 = kf * 16 + half * 8;
    short8 p0, p1;
#pragma unroll
    for (int j = 0; j < 8; ++j) {
      int k = k0 + j;
      p0[j] = (short)((k < EMBED) ? f2bf(kern[k * 2048 + gcol0]) : 0);
      p1[j] = (short)((k < EMBED) ? f2bf(kern[k * 2048 + gcol1]) : 0);
    }
    *(short8*)(sh_b2 + ((0 * KXF + kf) * 64 + lane) * 16) = p0;
    *(short8*)(sh_b2 + ((1 * KXF + kf) * 64 + lane) * 16) = p1;
  }

  const float bsi = bias[u], bsf = bias[512 + u], bsg = bias[1024 + u], bso = bias[1536 + u];

  // ---- init h/c; publish h(0) bf16 row-major into hb_[1] ----
  float hreg[16], creg[16];
#pragma unroll
  for (int r = 0; r < 16; ++r) {
    int rowl = (r & 3) + 8 * (r >> 2) + 4 * half;
    int brow = rb * 64 + w * 32 + rowl;
    float hv = h0[brow * 512 + u];
    float cv = c0[brow * 512 + u];
    hreg[r] = hv; creg[r] = cv;
    float hp = __shfl_xor(hv, 1, 64);
    if (lo && !(n & 1)) {
      unsigned d = (unsigned)f2bf(hv) | ((unsigned)f2bf(hp) << 16);
      g_store32((unsigned*)(hb_[1] + brow * 1024 + u * 2), d);
    }
  }

  __syncthreads();                    // drains vmcnt (publishes) + orders LDS weights
  if (tid == 0) g_store32(myflag, 1u);

  // A-row owned by this lane (for x frags): row w*32+n, k offset half*8
  const int myrow = rb * 64 + w * 32 + n;

#pragma unroll 1
  for (int t = 0; t < SEQ; ++t) {
    const char* hsrc = hb_[(t + 1) & 1];
    char*       hdst = hb_[t & 1];

    // ---- mask tokens for epilogue (cached loads, off the coherent path) ----
    int tok16[16];
#pragma unroll
    for (int r = 0; r < 16; ++r) {
      int rowl = (r & 3) + 8 * (r >> 2) + 4 * half;
      tok16[r] = seq[(rb * 64 + w * 32 + rowl) * SEQ + t];
    }

    floatx16 acc0, acc1;
#pragma unroll
    for (int i = 0; i < 16; ++i) { acc0[i] = 0.f; acc1[i] = 0.f; }

    // ---- x-part: A-frags straight from emb (normal cached loads), pre-poll ----
    {
      int tok = seq[myrow * SEQ + t];
      const float* erow = emb + tok * EMBED;
#pragma unroll
      for (int kf = 0; kf < KXF; ++kf) {
        short8 xf;
        if (kf < 18) {
          float4 e0 = *(const float4*)(erow + kf * 16 + half * 8);
          float4 e1 = *(const float4*)(erow + kf * 16 + half * 8 + 4);
          xf[0] = (short)f2bf(e0.x); xf[1] = (short)f2bf(e0.y);
          xf[2] = (short)f2bf(e0.z); xf[3] = (short)f2bf(e0.w);
          xf[4] = (short)f2bf(e1.x); xf[5] = (short)f2bf(e1.y);
          xf[6] = (short)f2bf(e1.z); xf[7] = (short)f2bf(e1.w);
        } else {
          // k = 288 + half*8 + j ; valid while < 300
          if (half == 0) {
            float4 e0 = *(const float4*)(erow + 288);
            float4 e1 = *(const float4*)(erow + 292);
            xf[0] = (short)f2bf(e0.x); xf[1] = (short)f2bf(e0.y);
            xf[2] = (short)f2bf(e0.z); xf[3] = (short)f2bf(e0.w);
            xf[4] = (short)f2bf(e1.x); xf[5] = (short)f2bf(e1.y);
            xf[6] = (short)f2bf(e1.z); xf[7] = (short)f2bf(e1.w);
          } else {
            float4 e0 = *(const float4*)(erow + 296);
            xf[0] = (short)f2bf(e0.x); xf[1] = (short)f2bf(e0.y);
            xf[2] = (short)f2bf(e0.z); xf[3] = (short)f2bf(e0.w);
            xf[4] = 0; xf[5] = 0; xf[6] = 0; xf[7] = 0;
          }
        }
        short8 p0 = *(const short8*)(sh_b2 + ((0 * KXF + kf) * 64 + lane) * 16);
        short8 p1 = *(const short8*)(sh_b2 + ((1 * KXF + kf) * 64 + lane) * 16);
        acc0 = __builtin_amdgcn_mfma_f32_32x32x16_bf16(xf, p0, acc0, 0, 0, 0);
        acc1 = __builtin_amdgcn_mfma_f32_32x32x16_bf16(xf, p1, acc1, 0, 0, 0);
      }
    }

    // ---- wait for h(t), then load + MFMA ----
    poll_ge(gflags, lane, (unsigned)(t + 1));

    const char* hrow = hsrc + (rb * 64 + w * 32 + n) * 1024 + half * 16;
    short8 hA[8], hB[8];
    LDH_GRP(hA, 0);
    LDH_GRP(hB, 8);
    MFMA_H_GRP(hA, 0);  LDH_GRP(hA, 16);
    MFMA_H_GRP(hB, 8);  LDH_GRP(hB, 24);
    MFMA_H_GRP(hA, 16);
    MFMA_H_GRP(hB, 24);

    // ---- epilogue: gates, state, mask, publish h(t+1) (coherent stores only) ----
#pragma unroll
    for (int r = 0; r < 16; ++r) {
      float a0 = acc0[r], a1 = acc1[r];
      float s0 = __shfl_xor(a0, 16, 64);
      float s1 = __shfl_xor(a1, 16, 64);
      float zi = (lo ? a0 : s0) + bsi;
      float zf = (lo ? s0 : a0) + bsf;
      float zg = (lo ? a1 : s1) + bsg;
      float zo = (lo ? s1 : a1) + bso;
      float iv = sigm(zi), fv = sigm(zf), gv = tanh_f(zg), ov = sigm(zo);
      float cn = fv * creg[r] + iv * gv;
      float hn = ov * tanh_f(cn);
      if (tok16[r] == 0) { cn = creg[r]; hn = hreg[r]; }
      creg[r] = cn; hreg[r] = hn;
      float hp = __shfl_xor(hn, 1, 64);
      if (lo && !(n & 1)) {
        int rowl = (r & 3) + 8 * (r >> 2) + 4 * half;
        int brow = rb * 64 + w * 32 + rowl;
        unsigned d = (unsigned)f2bf(hn) | ((unsigned)f2bf(hp) << 16);
        g_store32((unsigned*)(hdst + brow * 1024 + u * 2), d);
      }
    }

    // ---- drain publishes, arrive; out-stores AFTER arrive (off critical path) ----
    __syncthreads();
    if (t < SEQ - 1 && tid == 0) g_store32(myflag, (unsigned)(t + 2));

    if (lo) {
#pragma unroll
      for (int r = 0; r < 16; ++r) {
        int rowl = (r & 3) + 8 * (r >> 2) + 4 * half;
        int brow = rb * 64 + w * 32 + rowl;
        out[brow * (SEQ * 512) + t * 512 + u] = hreg[r];
        if (t == SEQ - 1) {
          out[BATCH * SEQ * 512 + brow * 512 + u] = hreg[r];
          out[BATCH * SEQ * 512 + BATCH * 512 + brow * 512 + u] = creg[r];
        }
      }
    }
  }
}

extern "C" void kernel_launch(void* const* d_in, const int* in_sizes, int n_in,
                              void* d_out, int out_size, void* d_ws, size_t ws_size,
                              hipStream_t stream) {
  if (ws_size < (size_t)WS_NEED) return;
  const int*   seq   = (const int*)d_in[0];
  const float* h0    = (const float*)d_in[1];
  const float* c0    = (const float*)d_in[2];
  const float* emb   = (const float*)d_in[3];
  const float* kern  = (const float*)d_in[4];
  const float* rkern = (const float*)d_in[5];
  const float* bias  = (const float*)d_in[6];
  float* out = (float*)d_out;

  hipFuncSetAttribute((const void*)lstm_enc,
                      hipFuncAttributeMaxDynamicSharedMemorySize, SMEM_BYTES);
  hipMemsetAsync(d_ws, 0, 65536, stream);  // zero barrier flags
  lstm_enc<<<dim3(256), dim3(128), SMEM_BYTES, stream>>>(
      seq, h0, c0, emb, kern, rkern, bias, out, (char*)d_ws);
}